// Round 1
// baseline (1774.893 us; speedup 1.0000x reference)
//
#include <hip/hip_runtime.h>

typedef short bf16x8 __attribute__((ext_vector_type(8)));
typedef float f32x4  __attribute__((ext_vector_type(4)));
typedef float fvec4  __attribute__((ext_vector_type(4)));
typedef unsigned short u16;
typedef unsigned int u32;
typedef u32 u32x4 __attribute__((ext_vector_type(4)));
typedef u16 u16x8 __attribute__((ext_vector_type(8)));

#define MFMA16(a,b,c) __builtin_amdgcn_mfma_f32_16x16x32_bf16((a),(b),(c),0,0,0)

__device__ __forceinline__ u16 f2bf(float f){
  u32 u = __float_as_uint(f);
  u32 r = (u + 0x7fffu + ((u >> 16) & 1u)) >> 16;   // RNE
  return (u16)r;
}
__device__ __forceinline__ float bf2f(u16 v){
  return __uint_as_float(((u32)v) << 16);
}
__device__ __forceinline__ void gload_lds16(const void* g, void* l){
  __builtin_amdgcn_global_load_lds((const __attribute__((address_space(1))) void*)g,
                                   (__attribute__((address_space(3))) void*)l, 16, 0, 0);
}

// ---------------------------------------------------------------------------
// RMSNorm: fp32 [M,2048] -> bf16 [M,2048], weight ln[2][2048], model by row>=split
// ---------------------------------------------------------------------------
__global__ __launch_bounds__(256) void rmsnorm_kernel(const float* __restrict__ x,
    const float* __restrict__ lnw, const int* __restrict__ splitp, u16* __restrict__ out)
{
  const int row = blockIdx.x, tid = threadIdx.x;
  const float* xr = x + (size_t)row*2048 + tid*8;
  fvec4 v0 = *(const fvec4*)xr;
  fvec4 v1 = *(const fvec4*)(xr + 4);
  float ss = v0[0]*v0[0] + v0[1]*v0[1] + v0[2]*v0[2] + v0[3]*v0[3]
           + v1[0]*v1[0] + v1[1]*v1[1] + v1[2]*v1[2] + v1[3]*v1[3];
  #pragma unroll
  for (int off=32; off; off>>=1) ss += __shfl_xor(ss, off, 64);
  __shared__ float red[4];
  if ((tid & 63) == 0) red[tid>>6] = ss;
  __syncthreads();
  float tot = red[0] + red[1] + red[2] + red[3];
  float rs = rsqrtf(tot * (1.0f/2048.0f) + 1.1920929e-07f);
  int model = (row >= splitp[0]) ? 1 : 0;
  const float* wr = lnw + model*2048 + tid*8;
  fvec4 w0 = *(const fvec4*)wr, w1 = *(const fvec4*)(wr+4);
  u32x4 pk;
  #pragma unroll
  for (int e=0;e<2;++e){
    pk[e]   = (u32)f2bf(v0[2*e]*rs*w0[2*e]) | ((u32)f2bf(v0[2*e+1]*rs*w0[2*e+1]) << 16);
    pk[2+e] = (u32)f2bf(v1[2*e]*rs*w1[2*e]) | ((u32)f2bf(v1[2*e+1]*rs*w1[2*e+1]) << 16);
  }
  *(u32x4*)(out + (size_t)row*2048 + tid*8) = pk;
}

// ---------------------------------------------------------------------------
// Routed GEMM: C[M,N] = A[M,K](bf16) @ W[model][K,N](fp32->bf16)
// 128x128 tile, BK=32, 4 waves (2x2 of 64x64), mfma 16x16x32 bf16.
// A staged via global_load_lds (pre-swizzled source), W reg-staged transposed
// into LDS [n][k] with XOR swizzle. RESID: out fp32 += residual; else out bf16.
// ---------------------------------------------------------------------------
template<int RESID>
__global__ __launch_bounds__(256) void gemm_routed(
    const u16* __restrict__ A, int lda, const float* __restrict__ Wall,
    int N, int K, const int* __restrict__ splitp,
    u16* __restrict__ outB, float* __restrict__ outF, const float* __restrict__ res)
{
  __shared__ char Asm[8192];   // [128 m][32 k] bf16, swizzled
  __shared__ char Bsm[8192];   // [128 n][32 k] bf16, swizzled
  const int tid = threadIdx.x;
  const int w = tid >> 6, l = tid & 63;
  const int ln = l & 15, g = l >> 4;
  const int wm = w >> 1, wn = w & 1;
  const int n0 = blockIdx.x * 128;
  const int row0 = blockIdx.y * 128;
  const int model = (row0 >= splitp[0]) ? 1 : 0;
  const float* W = Wall + (size_t)model * K * N;

  const int kpair = tid >> 4;          // 0..15 -> k = 2*kpair, 2*kpair+1
  const int nn = (tid & 15) * 8;       // 0..120

  f32x4 acc[4][4];
  #pragma unroll
  for (int i=0;i<4;++i)
    #pragma unroll
    for (int j=0;j<4;++j) acc[i][j] = f32x4{0.f,0.f,0.f,0.f};

  fvec4 br[4];
  const float* Wp0 = W + (size_t)(kpair*2) * N + n0 + nn;
  auto loadB = [&](int kt){
    const float* p = Wp0 + (size_t)kt * 32 * N;
    br[0] = *(const fvec4*)p;
    br[1] = *(const fvec4*)(p + 4);
    br[2] = *(const fvec4*)(p + N);
    br[3] = *(const fvec4*)(p + N + 4);
  };
  loadB(0);

  // per-lane A gll source decode (issue i): linear = (w*2+i)*1024 + l*16
  int arow[2], aj[2];
  #pragma unroll
  for (int i=0;i<2;++i){
    int lin = (w*2+i)*1024 + l*16;
    int r_ = lin >> 6;             // 64 B per row
    int s_ = (lin >> 4) & 3;       // 4 slots of 16B
    arow[i] = r_;
    aj[i] = s_ ^ (r_ & 3);         // pre-swizzled k-slot
  }

  const int nt = K / 32;
  for (int kt = 0; kt < nt; ++kt){
    __syncthreads();               // previous tile's reads complete
    #pragma unroll
    for (int i=0;i<2;++i){
      const u16* src = A + (size_t)(row0 + arow[i]) * lda + kt*32 + aj[i]*8;
      gload_lds16(src, Asm + (w*2+i)*1024);
    }
    // write W^T tile from regs (loaded previous iteration)
    #pragma unroll
    for (int e=0;e<8;++e){
      float lo = (e<4) ? br[0][e] : br[1][e-4];
      float hi = (e<4) ? br[2][e] : br[3][e-4];
      u32 pk = (u32)f2bf(lo) | ((u32)f2bf(hi) << 16);
      int n = nn + e;
      int byte = n*64 + ((((kpair>>2) ^ (n&3)) & 3) << 4) + ((kpair & 3) << 2);
      *(u32*)(Bsm + byte) = pk;
    }
    if (kt + 1 < nt) loadB(kt+1);  // prefetch next W tile into regs
    __syncthreads();               // staging visible (drains vmcnt+lgkm)

    bf16x8 a[4], b[4];
    #pragma unroll
    for (int mf=0;mf<4;++mf){
      int r_ = wm*64 + mf*16 + ln;
      a[mf] = *(const bf16x8*)(Asm + r_*64 + (((g ^ (r_&3)) & 3) << 4));
    }
    #pragma unroll
    for (int nf=0;nf<4;++nf){
      int r_ = wn*64 + nf*16 + ln;
      b[nf] = *(const bf16x8*)(Bsm + r_*64 + (((g ^ (r_&3)) & 3) << 4));
    }
    #pragma unroll
    for (int mf=0;mf<4;++mf)
      #pragma unroll
      for (int nf=0;nf<4;++nf)
        acc[mf][nf] = MFMA16(a[mf], b[nf], acc[mf][nf]);
  }

  // epilogue: C row = (lane>>4)*4+r, col = lane&15 within each 16x16 frag
  #pragma unroll
  for (int mf=0;mf<4;++mf){
    #pragma unroll
    for (int nf=0;nf<4;++nf){
      #pragma unroll
      for (int r=0;r<4;++r){
        int row = row0 + wm*64 + mf*16 + g*4 + r;
        int col = n0 + wn*64 + nf*16 + ln;
        size_t off = (size_t)row * N + col;
        float v = acc[mf][nf][r];
        if (RESID) outF[off] = v + res[off];
        else       outB[off] = f2bf(v);
      }
    }
  }
}

// ---------------------------------------------------------------------------
// Flash attention per (seg, head, 64-row Q tile). qkv bf16 [4096][6144]:
// q cols [0,2048) k [2048,4096) v [4096,6144). 16 heads x 128 dim.
// Each wave owns 16 q rows. KV tiles of 32, double-buffered.
// PV computed as O^T = V^T * P^T (both operands contiguous-k in LDS).
// ---------------------------------------------------------------------------
__global__ __launch_bounds__(256) void attn_kernel(const u16* __restrict__ qkv,
                                                   u16* __restrict__ out)
{
  __shared__ char Ksm[2][8192];   // [32 kv][128 d] bf16, 16-slot swizzle
  __shared__ char Vsm[2][8192];   // [128 d][32 kv] bf16, 4-slot swizzle
  __shared__ char Psm[4][1024];   // per wave [16 q][32 kv] bf16, 4-slot swizzle
  const int tid = threadIdx.x;
  const int w = tid >> 6, l = tid & 63;
  const int ln = l & 15, g = l >> 4;
  const int qt = blockIdx.x, h = blockIdx.y, seg = blockIdx.z;
  const int srow = seg * 2048;
  const float scale = 0.08838834764831845f;   // 1/sqrt(128)

  const int qrow = srow + qt*64 + w*16 + ln;
  bf16x8 qf[4];
  #pragma unroll
  for (int c=0;c<4;++c)
    qf[c] = *(const bf16x8*)(qkv + (size_t)qrow*6144 + h*128 + c*32 + g*8);

  f32x4 oacc[8];
  #pragma unroll
  for (int i=0;i<8;++i) oacc[i] = f32x4{0.f,0.f,0.f,0.f};
  float m[4]    = {-1e30f,-1e30f,-1e30f,-1e30f};
  float lsum[4] = {0.f,0.f,0.f,0.f};

  int kkv[2], ks[2];
  #pragma unroll
  for (int i=0;i<2;++i){
    int lin = (w*2+i)*1024 + l*16;
    int kv = lin >> 8;             // 256 B per kv row
    int sp = (lin >> 4) & 15;
    kkv[i] = kv;
    ks[i] = sp ^ (kv & 15);        // pre-swizzled d-slot
  }
  const int vkv = tid >> 3, vd0 = (tid & 7) * 16;

  bf16x8 vreg0, vreg1;
  auto stage = [&](int kv0, int buf){
    #pragma unroll
    for (int i=0;i<2;++i){
      const u16* src = qkv + (size_t)(srow + kv0 + kkv[i]) * 6144 + 2048 + h*128 + ks[i]*8;
      gload_lds16(src, Ksm[buf] + (w*2+i)*1024);
    }
    const u16* vs = qkv + (size_t)(srow + kv0 + vkv) * 6144 + 4096 + h*128 + vd0;
    vreg0 = *(const bf16x8*)vs;
    vreg1 = *(const bf16x8*)(vs + 8);
  };
  auto writeV = [&](int buf){
    #pragma unroll
    for (int e=0;e<16;++e){
      int d = vd0 + e;
      u16 val = (u16)((e<8) ? vreg0[e] : vreg1[e-8]);
      int byte = d*64 + ((((vkv>>3) ^ (d&3)) & 3) << 4) + ((vkv & 7) << 1);
      *(u16*)(Vsm[buf] + byte) = val;
    }
  };

  stage(0, 0);
  writeV(0);
  __syncthreads();

  for (int t=0; t<64; ++t){
    int cur = t & 1, nxt = cur ^ 1;
    if (t+1 < 64) stage((t+1)*32, nxt);   // prefetch next KV

    // S = Q K^T over d=128 (two 16-col halves)
    f32x4 s0 = f32x4{0.f,0.f,0.f,0.f}, s1 = f32x4{0.f,0.f,0.f,0.f};
    #pragma unroll
    for (int c=0;c<4;++c){
      int sl = c*4 + g;
      int c0 = ln;
      bf16x8 k0 = *(const bf16x8*)(Ksm[cur] + c0*256 + (((sl ^ (c0&15)) & 15) << 4));
      s0 = MFMA16(qf[c], k0, s0);
      int c1 = 16 + ln;
      bf16x8 k1 = *(const bf16x8*)(Ksm[cur] + c1*256 + (((sl ^ (c1&15)) & 15) << 4));
      s1 = MFMA16(qf[c], k1, s1);
    }
    float mx[4], f_[4];
    #pragma unroll
    for (int r=0;r<4;++r){
      s0[r] *= scale; s1[r] *= scale;
      mx[r] = fmaxf(s0[r], s1[r]);
    }
    #pragma unroll
    for (int off=1; off<16; off<<=1){
      #pragma unroll
      for (int r=0;r<4;++r) mx[r] = fmaxf(mx[r], __shfl_xor(mx[r], off, 64));
    }
    #pragma unroll
    for (int r=0;r<4;++r){
      float mn = fmaxf(m[r], mx[r]);
      f_[r] = __expf(m[r] - mn);
      m[r] = mn;
      lsum[r] *= f_[r];
    }
    // P = exp(S - m), stash to per-wave LDS (rows g*4+r, cols ln / 16+ln)
    #pragma unroll
    for (int r=0;r<4;++r){
      float p0 = __expf(s0[r] - m[r]);
      float p1 = __expf(s1[r] - m[r]);
      lsum[r] += p0 + p1;
      int qq = g*4 + r;
      int c0 = ln, c1 = 16 + ln;
      *(u16*)(Psm[w] + qq*64 + ((((c0>>3) ^ (qq&3)) & 3) << 4) + ((c0&7)<<1)) = f2bf(p0);
      *(u16*)(Psm[w] + qq*64 + ((((c1>>3) ^ (qq&3)) & 3) << 4) + ((c1&7)<<1)) = f2bf(p1);
    }
    // redistribute rescale factor to O^T column layout (col q = ln)
    {
      int srcl = (ln >> 2) << 4;
      float F0 = __shfl(f_[0], srcl, 64);
      float F1 = __shfl(f_[1], srcl, 64);
      float F2 = __shfl(f_[2], srcl, 64);
      float F3 = __shfl(f_[3], srcl, 64);
      int rr = ln & 3;
      float fc = (rr==0) ? F0 : (rr==1) ? F1 : (rr==2) ? F2 : F3;
      #pragma unroll
      for (int mc=0;mc<8;++mc){
        #pragma unroll
        for (int r=0;r<4;++r) oacc[mc][r] *= fc;
      }
    }
    // O^T += V^T * P^T
    bf16x8 pf = *(const bf16x8*)(Psm[w] + ln*64 + (((g ^ (ln&3)) & 3) << 4));
    #pragma unroll
    for (int mc=0;mc<8;++mc){
      int d = mc*16 + ln;
      bf16x8 vf = *(const bf16x8*)(Vsm[cur] + d*64 + (((g ^ (d&3)) & 3) << 4));
      oacc[mc] = MFMA16(vf, pf, oacc[mc]);
    }
    if (t+1 < 64) writeV(nxt);
    __syncthreads();
  }

  // final: full row sums, redistribute to column layout, normalize, store
  #pragma unroll
  for (int off=1; off<16; off<<=1){
    #pragma unroll
    for (int r=0;r<4;++r) lsum[r] += __shfl_xor(lsum[r], off, 64);
  }
  int srcl = (ln >> 2) << 4;
  float L0 = __shfl(lsum[0], srcl, 64);
  float L1 = __shfl(lsum[1], srcl, 64);
  float L2 = __shfl(lsum[2], srcl, 64);
  float L3 = __shfl(lsum[3], srcl, 64);
  int rr = ln & 3;
  float Lc = (rr==0) ? L0 : (rr==1) ? L1 : (rr==2) ? L2 : L3;
  float linv = 1.0f / Lc;
  const int orow = srow + qt*64 + w*16 + ln;
  #pragma unroll
  for (int mc=0;mc<8;++mc){
    #pragma unroll
    for (int r=0;r<4;++r){
      int d = mc*16 + g*4 + r;
      out[(size_t)orow*2048 + h*128 + d] = f2bf(oacc[mc][r] * linv);
    }
  }
}

// ---------------------------------------------------------------------------
// SwiGLU: hm[i,j] = silu(gu[i,j]) * gu[i,FF+j], FF=5504, all bf16
// ---------------------------------------------------------------------------
__global__ __launch_bounds__(256) void silu_kernel(const u16* __restrict__ gu,
                                                   u16* __restrict__ hm)
{
  int u = blockIdx.x*256 + threadIdx.x;
  if (u >= 4096*688) return;
  int row = u / 688;
  int j = (u - row*688) * 8;
  const u16* gp = gu + (size_t)row*11008 + j;
  u16x8 gv = *(const u16x8*)gp;
  u16x8 uv = *(const u16x8*)(gp + 5504);
  u32x4 pk;
  #pragma unroll
  for (int e=0;e<4;++e){
    float g0 = bf2f(gv[2*e]),   g1 = bf2f(gv[2*e+1]);
    float u0 = bf2f(uv[2*e]),   u1 = bf2f(uv[2*e+1]);
    float r0 = g0 / (1.f + __expf(-g0)) * u0;
    float r1 = g1 / (1.f + __expf(-g1)) * u1;
    pk[e] = (u32)f2bf(r0) | ((u32)f2bf(r1) << 16);
  }
  *(u32x4*)(hm + (size_t)row*5504 + j) = pk;
}

// ---------------------------------------------------------------------------
extern "C" void kernel_launch(void* const* d_in, const int* in_sizes, int n_in,
                              void* d_out, int out_size, void* d_ws, size_t ws_size,
                              hipStream_t stream) {
  const float* x    = (const float*)d_in[0];
  const float* Wqkv = (const float*)d_in[1];
  const float* Wo   = (const float*)d_in[2];
  const float* Wgu  = (const float*)d_in[3];
  const float* Wd   = (const float*)d_in[4];
  const float* ln1  = (const float*)d_in[5];
  const float* ln2  = (const float*)d_in[6];
  const int*   split= (const int*)d_in[7];
  float* out = (float*)d_out;

  // workspace layout (bytes); total 235,929,600 (~225 MiB)
  char* ws = (char*)d_ws;
  u16* h    = (u16*)(ws);                  // [4096][2048]  16.78 MB
  u16* qkv  = (u16*)(ws + 16777216);       // [4096][6144]  50.33 MB
  u16* attn = (u16*)(ws + 67108864);       // [4096][2048]  16.78 MB
  u16* h2   = (u16*)(ws + 83886080);       // [4096][2048]  16.78 MB
  u16* gu   = (u16*)(ws + 100663296);      // [4096][11008] 90.18 MB
  u16* hm   = (u16*)(ws + 190840832);      // [4096][5504]  45.09 MB

  // 1. h = rmsnorm(x, ln1)
  rmsnorm_kernel<<<4096, 256, 0, stream>>>(x, ln1, split, h);
  // 2. qkv = h @ W_qkv[model]
  gemm_routed<0><<<dim3(48, 32), 256, 0, stream>>>(h, 2048, Wqkv, 6144, 2048, split,
                                                   qkv, nullptr, nullptr);
  // 3. attention per segment/head
  attn_kernel<<<dim3(32, 16, 2), 256, 0, stream>>>(qkv, attn);
  // 4. x1 = x + attn @ W_o[model]   (x1 lives in d_out)
  gemm_routed<1><<<dim3(16, 32), 256, 0, stream>>>(attn, 2048, Wo, 2048, 2048, split,
                                                   nullptr, out, x);
  // 5. h2 = rmsnorm(x1, ln2)
  rmsnorm_kernel<<<4096, 256, 0, stream>>>(out, ln2, split, h2);
  // 6. gu = h2 @ W_gu[model]
  gemm_routed<0><<<dim3(86, 32), 256, 0, stream>>>(h2, 2048, Wgu, 11008, 2048, split,
                                                   gu, nullptr, nullptr);
  // 7. hm = silu(gate) * up
  silu_kernel<<<11008, 256, 0, stream>>>(gu, hm);
  // 8. out = x1 + hm @ W_d[model]
  gemm_routed<1><<<dim3(16, 32), 256, 0, stream>>>(hm, 5504, Wd, 2048, 5504, split,
                                                   nullptr, out, out);
}

// Round 2
// 1365.468 us; speedup vs baseline: 1.2998x; 1.2998x over previous
//
#include <hip/hip_runtime.h>

typedef short bf16x8 __attribute__((ext_vector_type(8)));
typedef float f32x4  __attribute__((ext_vector_type(4)));
typedef float fvec4  __attribute__((ext_vector_type(4)));
typedef unsigned short u16;
typedef unsigned int u32;
typedef u32 u32x4 __attribute__((ext_vector_type(4)));
typedef u16 u16x8 __attribute__((ext_vector_type(8)));

#define MFMA16(a,b,c) __builtin_amdgcn_mfma_f32_16x16x32_bf16((a),(b),(c),0,0,0)

__device__ __forceinline__ u16 f2bf(float f){
  u32 u = __float_as_uint(f);
  u32 r = (u + 0x7fffu + ((u >> 16) & 1u)) >> 16;   // RNE
  return (u16)r;
}
__device__ __forceinline__ float bf2f(u16 v){
  return __uint_as_float(((u32)v) << 16);
}
__device__ __forceinline__ void gload_lds16(const void* g, void* l){
  __builtin_amdgcn_global_load_lds((const __attribute__((address_space(1))) void*)g,
                                   (__attribute__((address_space(3))) void*)l, 16, 0, 0);
}

// ---------------------------------------------------------------------------
// RMSNorm: fp32 [M,2048] -> bf16 [M,2048], weight ln[2][2048], model by row>=split
// ---------------------------------------------------------------------------
__global__ __launch_bounds__(256) void rmsnorm_kernel(const float* __restrict__ x,
    const float* __restrict__ lnw, const int* __restrict__ splitp, u16* __restrict__ out)
{
  const int row = blockIdx.x, tid = threadIdx.x;
  const float* xr = x + (size_t)row*2048 + tid*8;
  fvec4 v0 = *(const fvec4*)xr;
  fvec4 v1 = *(const fvec4*)(xr + 4);
  float ss = v0[0]*v0[0] + v0[1]*v0[1] + v0[2]*v0[2] + v0[3]*v0[3]
           + v1[0]*v1[0] + v1[1]*v1[1] + v1[2]*v1[2] + v1[3]*v1[3];
  #pragma unroll
  for (int off=32; off; off>>=1) ss += __shfl_xor(ss, off, 64);
  __shared__ float red[4];
  if ((tid & 63) == 0) red[tid>>6] = ss;
  __syncthreads();
  float tot = red[0] + red[1] + red[2] + red[3];
  float rs = rsqrtf(tot * (1.0f/2048.0f) + 1.1920929e-07f);
  int model = (row >= splitp[0]) ? 1 : 0;
  const float* wr = lnw + model*2048 + tid*8;
  fvec4 w0 = *(const fvec4*)wr, w1 = *(const fvec4*)(wr+4);
  u32x4 pk;
  #pragma unroll
  for (int e=0;e<2;++e){
    pk[e]   = (u32)f2bf(v0[2*e]*rs*w0[2*e]) | ((u32)f2bf(v0[2*e+1]*rs*w0[2*e+1]) << 16);
    pk[2+e] = (u32)f2bf(v1[2*e]*rs*w1[2*e]) | ((u32)f2bf(v1[2*e+1]*rs*w1[2*e+1]) << 16);
  }
  *(u32x4*)(out + (size_t)row*2048 + tid*8) = pk;
}

// ---------------------------------------------------------------------------
// Weight transpose+convert: W[model][K][N] fp32 -> Wt[model][N][K] bf16
// 32x32 tiles via LDS, coalesced both sides.
// ---------------------------------------------------------------------------
__global__ __launch_bounds__(256) void transpose_w(const float* __restrict__ W,
    u16* __restrict__ Wt, int K, int N)
{
  __shared__ float t[32][33];
  const int n0 = blockIdx.x * 32, k0 = blockIdx.y * 32;
  const float* Wm = W + (size_t)blockIdx.z * K * N;
  u16* Wtm = Wt + (size_t)blockIdx.z * K * N;
  const int tx = threadIdx.x & 31, ty = threadIdx.x >> 5;
  #pragma unroll
  for (int p=0;p<4;++p){
    int k = ty + p*8;
    t[k][tx] = Wm[(size_t)(k0 + k) * N + n0 + tx];
  }
  __syncthreads();
  #pragma unroll
  for (int p=0;p<4;++p){
    int n = ty + p*8;
    Wtm[(size_t)(n0 + n) * K + k0 + tx] = f2bf(t[tx][n]);
  }
}

// ---------------------------------------------------------------------------
// Routed GEMM: C[M,N] = A[M,K](bf16) @ Wt[model][N][K](bf16, pre-transposed)
// 128x128 tile, BK=32, 4 waves (2x2 of 64x64), mfma 16x16x32 bf16.
// Both operands staged via global_load_lds width=16 with pre-swizzled source.
// Grid: x = M-tile (row-fastest: consecutive blocks share the same W panel
// -> W HBM-fetched ~once), y = N-tile.
// RESID: out fp32 += residual; else out bf16.
// ---------------------------------------------------------------------------
template<int RESID>
__global__ __launch_bounds__(256) void gemm_routed(
    const u16* __restrict__ A, int lda, const u16* __restrict__ Wt,
    int N, int K, const int* __restrict__ splitp,
    u16* __restrict__ outB, float* __restrict__ outF, const float* __restrict__ res)
{
  __shared__ char Asm[8192];   // [128 m][32 k] bf16, 4-slot XOR swizzle
  __shared__ char Bsm[8192];   // [128 n][32 k] bf16, same swizzle
  const int tid = threadIdx.x;
  const int w = tid >> 6, l = tid & 63;
  const int ln = l & 15, g = l >> 4;
  const int wm = w >> 1, wn = w & 1;
  const int row0 = blockIdx.x * 128;   // M-tile fastest
  const int n0 = blockIdx.y * 128;
  const int model = (row0 >= splitp[0]) ? 1 : 0;
  const u16* B = Wt + (size_t)model * N * K;

  f32x4 acc[4][4];
  #pragma unroll
  for (int i=0;i<4;++i)
    #pragma unroll
    for (int j=0;j<4;++j) acc[i][j] = f32x4{0.f,0.f,0.f,0.f};

  // per-lane gll source decode (issue i): linear dest = (w*2+i)*1024 + l*16
  int arow[2], aj[2];
  #pragma unroll
  for (int i=0;i<2;++i){
    int lin = (w*2+i)*1024 + l*16;
    int r_ = lin >> 6;             // 64 B per row
    int s_ = (lin >> 4) & 3;       // 4 slots of 16B
    arow[i] = r_;
    aj[i] = s_ ^ (r_ & 3);         // pre-swizzled k-slot
  }

  const int nt = K / 32;
  for (int kt = 0; kt < nt; ++kt){
    __syncthreads();               // previous tile's reads complete
    #pragma unroll
    for (int i=0;i<2;++i){
      const u16* srcA = A + (size_t)(row0 + arow[i]) * lda + kt*32 + aj[i]*8;
      gload_lds16(srcA, Asm + (w*2+i)*1024);
      const u16* srcB = B + (size_t)(n0 + arow[i]) * K + kt*32 + aj[i]*8;
      gload_lds16(srcB, Bsm + (w*2+i)*1024);
    }
    __syncthreads();               // staging visible (drains vmcnt+lgkm)

    bf16x8 a[4], b[4];
    #pragma unroll
    for (int mf=0;mf<4;++mf){
      int r_ = wm*64 + mf*16 + ln;
      a[mf] = *(const bf16x8*)(Asm + r_*64 + (((g ^ (r_&3)) & 3) << 4));
    }
    #pragma unroll
    for (int nf=0;nf<4;++nf){
      int r_ = wn*64 + nf*16 + ln;
      b[nf] = *(const bf16x8*)(Bsm + r_*64 + (((g ^ (r_&3)) & 3) << 4));
    }
    #pragma unroll
    for (int mf=0;mf<4;++mf)
      #pragma unroll
      for (int nf=0;nf<4;++nf)
        acc[mf][nf] = MFMA16(a[mf], b[nf], acc[mf][nf]);
  }

  // epilogue: C row = (lane>>4)*4+r, col = lane&15 within each 16x16 frag
  #pragma unroll
  for (int mf=0;mf<4;++mf){
    #pragma unroll
    for (int nf=0;nf<4;++nf){
      #pragma unroll
      for (int r=0;r<4;++r){
        int row = row0 + wm*64 + mf*16 + g*4 + r;
        int col = n0 + wn*64 + nf*16 + ln;
        size_t off = (size_t)row * N + col;
        float v = acc[mf][nf][r];
        if (RESID) outF[off] = v + res[off];
        else       outB[off] = f2bf(v);
      }
    }
  }
}

// ---------------------------------------------------------------------------
// Flash attention per (seg, head, 64-row Q tile). qkv bf16 [4096][6144]:
// q cols [0,2048) k [2048,4096) v [4096,6144). 16 heads x 128 dim.
// Each wave owns 16 q rows. KV tiles of 32, double-buffered.
// PV computed as O^T = V^T * P^T (both operands contiguous-k in LDS).
// ---------------------------------------------------------------------------
__global__ __launch_bounds__(256) void attn_kernel(const u16* __restrict__ qkv,
                                                   u16* __restrict__ out)
{
  __shared__ char Ksm[2][8192];   // [32 kv][128 d] bf16, 16-slot swizzle
  __shared__ char Vsm[2][8192];   // [128 d][32 kv] bf16, 4-slot swizzle
  __shared__ char Psm[4][1024];   // per wave [16 q][32 kv] bf16, 4-slot swizzle
  const int tid = threadIdx.x;
  const int w = tid >> 6, l = tid & 63;
  const int ln = l & 15, g = l >> 4;
  const int qt = blockIdx.x, h = blockIdx.y, seg = blockIdx.z;
  const int srow = seg * 2048;
  const float scale = 0.08838834764831845f;   // 1/sqrt(128)

  const int qrow = srow + qt*64 + w*16 + ln;
  bf16x8 qf[4];
  #pragma unroll
  for (int c=0;c<4;++c)
    qf[c] = *(const bf16x8*)(qkv + (size_t)qrow*6144 + h*128 + c*32 + g*8);

  f32x4 oacc[8];
  #pragma unroll
  for (int i=0;i<8;++i) oacc[i] = f32x4{0.f,0.f,0.f,0.f};
  float m[4]    = {-1e30f,-1e30f,-1e30f,-1e30f};
  float lsum[4] = {0.f,0.f,0.f,0.f};

  int kkv[2], ks[2];
  #pragma unroll
  for (int i=0;i<2;++i){
    int lin = (w*2+i)*1024 + l*16;
    int kv = lin >> 8;             // 256 B per kv row
    int sp = (lin >> 4) & 15;
    kkv[i] = kv;
    ks[i] = sp ^ (kv & 15);        // pre-swizzled d-slot
  }
  const int vkv = tid >> 3, vd0 = (tid & 7) * 16;

  bf16x8 vreg0, vreg1;
  auto stage = [&](int kv0, int buf){
    #pragma unroll
    for (int i=0;i<2;++i){
      const u16* src = qkv + (size_t)(srow + kv0 + kkv[i]) * 6144 + 2048 + h*128 + ks[i]*8;
      gload_lds16(src, Ksm[buf] + (w*2+i)*1024);
    }
    const u16* vs = qkv + (size_t)(srow + kv0 + vkv) * 6144 + 4096 + h*128 + vd0;
    vreg0 = *(const bf16x8*)vs;
    vreg1 = *(const bf16x8*)(vs + 8);
  };
  auto writeV = [&](int buf){
    #pragma unroll
    for (int e=0;e<16;++e){
      int d = vd0 + e;
      u16 val = (u16)((e<8) ? vreg0[e] : vreg1[e-8]);
      int byte = d*64 + ((((vkv>>3) ^ (d&3)) & 3) << 4) + ((vkv & 7) << 1);
      *(u16*)(Vsm[buf] + byte) = val;
    }
  };

  stage(0, 0);
  writeV(0);
  __syncthreads();

  for (int t=0; t<64; ++t){
    int cur = t & 1, nxt = cur ^ 1;
    if (t+1 < 64) stage((t+1)*32, nxt);   // prefetch next KV

    // S = Q K^T over d=128 (two 16-col halves)
    f32x4 s0 = f32x4{0.f,0.f,0.f,0.f}, s1 = f32x4{0.f,0.f,0.f,0.f};
    #pragma unroll
    for (int c=0;c<4;++c){
      int sl = c*4 + g;
      int c0 = ln;
      bf16x8 k0 = *(const bf16x8*)(Ksm[cur] + c0*256 + (((sl ^ (c0&15)) & 15) << 4));
      s0 = MFMA16(qf[c], k0, s0);
      int c1 = 16 + ln;
      bf16x8 k1 = *(const bf16x8*)(Ksm[cur] + c1*256 + (((sl ^ (c1&15)) & 15) << 4));
      s1 = MFMA16(qf[c], k1, s1);
    }
    float mx[4], f_[4];
    #pragma unroll
    for (int r=0;r<4;++r){
      s0[r] *= scale; s1[r] *= scale;
      mx[r] = fmaxf(s0[r], s1[r]);
    }
    #pragma unroll
    for (int off=1; off<16; off<<=1){
      #pragma unroll
      for (int r=0;r<4;++r) mx[r] = fmaxf(mx[r], __shfl_xor(mx[r], off, 64));
    }
    #pragma unroll
    for (int r=0;r<4;++r){
      float mn = fmaxf(m[r], mx[r]);
      f_[r] = __expf(m[r] - mn);
      m[r] = mn;
      lsum[r] *= f_[r];
    }
    // P = exp(S - m), stash to per-wave LDS (rows g*4+r, cols ln / 16+ln)
    #pragma unroll
    for (int r=0;r<4;++r){
      float p0 = __expf(s0[r] - m[r]);
      float p1 = __expf(s1[r] - m[r]);
      lsum[r] += p0 + p1;
      int qq = g*4 + r;
      int c0 = ln, c1 = 16 + ln;
      *(u16*)(Psm[w] + qq*64 + ((((c0>>3) ^ (qq&3)) & 3) << 4) + ((c0&7)<<1)) = f2bf(p0);
      *(u16*)(Psm[w] + qq*64 + ((((c1>>3) ^ (qq&3)) & 3) << 4) + ((c1&7)<<1)) = f2bf(p1);
    }
    // redistribute rescale factor to O^T column layout (col q = ln)
    {
      int srcl = (ln >> 2) << 4;
      float F0 = __shfl(f_[0], srcl, 64);
      float F1 = __shfl(f_[1], srcl, 64);
      float F2 = __shfl(f_[2], srcl, 64);
      float F3 = __shfl(f_[3], srcl, 64);
      int rr = ln & 3;
      float fc = (rr==0) ? F0 : (rr==1) ? F1 : (rr==2) ? F2 : F3;
      #pragma unroll
      for (int mc=0;mc<8;++mc){
        #pragma unroll
        for (int r=0;r<4;++r) oacc[mc][r] *= fc;
      }
    }
    // O^T += V^T * P^T
    bf16x8 pf = *(const bf16x8*)(Psm[w] + ln*64 + (((g ^ (ln&3)) & 3) << 4));
    #pragma unroll
    for (int mc=0;mc<8;++mc){
      int d = mc*16 + ln;
      bf16x8 vf = *(const bf16x8*)(Vsm[cur] + d*64 + (((g ^ (d&3)) & 3) << 4));
      oacc[mc] = MFMA16(vf, pf, oacc[mc]);
    }
    if (t+1 < 64) writeV(nxt);
    __syncthreads();
  }

  // final: full row sums, redistribute to column layout, normalize, store
  #pragma unroll
  for (int off=1; off<16; off<<=1){
    #pragma unroll
    for (int r=0;r<4;++r) lsum[r] += __shfl_xor(lsum[r], off, 64);
  }
  int srcl = (ln >> 2) << 4;
  float L0 = __shfl(lsum[0], srcl, 64);
  float L1 = __shfl(lsum[1], srcl, 64);
  float L2 = __shfl(lsum[2], srcl, 64);
  float L3 = __shfl(lsum[3], srcl, 64);
  int rr = ln & 3;
  float Lc = (rr==0) ? L0 : (rr==1) ? L1 : (rr==2) ? L2 : L3;
  float linv = 1.0f / Lc;
  const int orow = srow + qt*64 + w*16 + ln;
  #pragma unroll
  for (int mc=0;mc<8;++mc){
    #pragma unroll
    for (int r=0;r<4;++r){
      int d = mc*16 + g*4 + r;
      out[(size_t)orow*2048 + h*128 + d] = f2bf(oacc[mc][r] * linv);
    }
  }
}

// ---------------------------------------------------------------------------
// SwiGLU: hm[i,j] = silu(gu[i,j]) * gu[i,FF+j], FF=5504, all bf16
// ---------------------------------------------------------------------------
__global__ __launch_bounds__(256) void silu_kernel(const u16* __restrict__ gu,
                                                   u16* __restrict__ hm)
{
  int u = blockIdx.x*256 + threadIdx.x;
  if (u >= 4096*688) return;
  int row = u / 688;
  int j = (u - row*688) * 8;
  const u16* gp = gu + (size_t)row*11008 + j;
  u16x8 gv = *(const u16x8*)gp;
  u16x8 uv = *(const u16x8*)(gp + 5504);
  u32x4 pk;
  #pragma unroll
  for (int e=0;e<4;++e){
    float g0 = bf2f(gv[2*e]),   g1 = bf2f(gv[2*e+1]);
    float u0 = bf2f(uv[2*e]),   u1 = bf2f(uv[2*e+1]);
    float r0 = g0 / (1.f + __expf(-g0)) * u0;
    float r1 = g1 / (1.f + __expf(-g1)) * u1;
    pk[e] = (u32)f2bf(r0) | ((u32)f2bf(r1) << 16);
  }
  *(u32x4*)(hm + (size_t)row*5504 + j) = pk;
}

// ---------------------------------------------------------------------------
extern "C" void kernel_launch(void* const* d_in, const int* in_sizes, int n_in,
                              void* d_out, int out_size, void* d_ws, size_t ws_size,
                              hipStream_t stream) {
  const float* x    = (const float*)d_in[0];
  const float* Wqkv = (const float*)d_in[1];
  const float* Wo   = (const float*)d_in[2];
  const float* Wgu  = (const float*)d_in[3];
  const float* Wd   = (const float*)d_in[4];
  const float* ln1  = (const float*)d_in[5];
  const float* ln2  = (const float*)d_in[6];
  const int*   split= (const int*)d_in[7];
  float* out = (float*)d_out;

  // workspace layout (bytes); total 268,435,456 (256 MiB)
  char* ws = (char*)d_ws;
  u16* Wt   = (u16*)(ws);                  // shared transposed-weight scratch, <= 90.18 MB
  u16* h    = (u16*)(ws + 94371840);       // [4096][2048] 16.78 MB (also h2)
  u16* qkv  = (u16*)(ws + 111149056);      // [4096][6144] 50.33 MB (also hm)
  u16* attn = (u16*)(ws + 161480704);      // [4096][2048] 16.78 MB
  u16* gu   = (u16*)(ws + 178257920);      // [4096][11008] 90.18 MB
  u16* h2   = h;
  u16* hm   = qkv;

  // 1. h = rmsnorm(x, ln1)
  rmsnorm_kernel<<<4096, 256, 0, stream>>>(x, ln1, split, h);
  // 2. qkv = h @ W_qkv[model]
  transpose_w<<<dim3(192, 64, 2), 256, 0, stream>>>(Wqkv, Wt, 2048, 6144);
  gemm_routed<0><<<dim3(32, 48), 256, 0, stream>>>(h, 2048, Wt, 6144, 2048, split,
                                                   qkv, nullptr, nullptr);
  // 3. attention per segment/head
  attn_kernel<<<dim3(32, 16, 2), 256, 0, stream>>>(qkv, attn);
  // 4. x1 = x + attn @ W_o[model]   (x1 lives in d_out)
  transpose_w<<<dim3(64, 64, 2), 256, 0, stream>>>(Wo, Wt, 2048, 2048);
  gemm_routed<1><<<dim3(32, 16), 256, 0, stream>>>(attn, 2048, Wt, 2048, 2048, split,
                                                   nullptr, out, x);
  // 5. h2 = rmsnorm(x1, ln2)
  rmsnorm_kernel<<<4096, 256, 0, stream>>>(out, ln2, split, h2);
  // 6. gu = h2 @ W_gu[model]
  transpose_w<<<dim3(344, 64, 2), 256, 0, stream>>>(Wgu, Wt, 2048, 11008);
  gemm_routed<0><<<dim3(32, 86), 256, 0, stream>>>(h2, 2048, Wt, 11008, 2048, split,
                                                   gu, nullptr, nullptr);
  // 7. hm = silu(gate) * up
  silu_kernel<<<11008, 256, 0, stream>>>(gu, hm);
  // 8. out = x1 + hm @ W_d[model]
  transpose_w<<<dim3(64, 172, 2), 256, 0, stream>>>(Wd, Wt, 5504, 2048);
  gemm_routed<1><<<dim3(32, 16), 256, 0, stream>>>(hm, 5504, Wt, 2048, 5504, split,
                                                   nullptr, out, out);
}

// Round 4
// 1261.697 us; speedup vs baseline: 1.4068x; 1.0822x over previous
//
#include <hip/hip_runtime.h>

typedef short bf16x8 __attribute__((ext_vector_type(8)));
typedef float f32x4  __attribute__((ext_vector_type(4)));
typedef float fvec4  __attribute__((ext_vector_type(4)));
typedef unsigned short u16;
typedef unsigned int u32;
typedef u32 u32x4 __attribute__((ext_vector_type(4)));
typedef u16 u16x8 __attribute__((ext_vector_type(8)));
typedef u16 u16x4 __attribute__((ext_vector_type(4)));

#define MFMA16(a,b,c) __builtin_amdgcn_mfma_f32_16x16x32_bf16((a),(b),(c),0,0,0)

__device__ __forceinline__ u16 f2bf(float f){
  u32 u = __float_as_uint(f);
  u32 r = (u + 0x7fffu + ((u >> 16) & 1u)) >> 16;   // RNE
  return (u16)r;
}
__device__ __forceinline__ float bf2f(u16 v){
  return __uint_as_float(((u32)v) << 16);
}
__device__ __forceinline__ void gload_lds16(const void* g, void* l){
  __builtin_amdgcn_global_load_lds((const __attribute__((address_space(1))) void*)g,
                                   (__attribute__((address_space(3))) void*)l, 16, 0, 0);
}

// ---------------------------------------------------------------------------
// RMSNorm: fp32 [M,2048] -> bf16 [M,2048], weight ln[2][2048], model by row>=split
// ---------------------------------------------------------------------------
__global__ __launch_bounds__(256) void rmsnorm_kernel(const float* __restrict__ x,
    const float* __restrict__ lnw, const int* __restrict__ splitp, u16* __restrict__ out)
{
  const int row = blockIdx.x, tid = threadIdx.x;
  const float* xr = x + (size_t)row*2048 + tid*8;
  fvec4 v0 = *(const fvec4*)xr;
  fvec4 v1 = *(const fvec4*)(xr + 4);
  float ss = v0[0]*v0[0] + v0[1]*v0[1] + v0[2]*v0[2] + v0[3]*v0[3]
           + v1[0]*v1[0] + v1[1]*v1[1] + v1[2]*v1[2] + v1[3]*v1[3];
  #pragma unroll
  for (int off=32; off; off>>=1) ss += __shfl_xor(ss, off, 64);
  __shared__ float red[4];
  if ((tid & 63) == 0) red[tid>>6] = ss;
  __syncthreads();
  float tot = red[0] + red[1] + red[2] + red[3];
  float rs = rsqrtf(tot * (1.0f/2048.0f) + 1.1920929e-07f);
  int model = (row >= splitp[0]) ? 1 : 0;
  const float* wr = lnw + model*2048 + tid*8;
  fvec4 w0 = *(const fvec4*)wr, w1 = *(const fvec4*)(wr+4);
  u32x4 pk;
  #pragma unroll
  for (int e=0;e<2;++e){
    pk[e]   = (u32)f2bf(v0[2*e]*rs*w0[2*e]) | ((u32)f2bf(v0[2*e+1]*rs*w0[2*e+1]) << 16);
    pk[2+e] = (u32)f2bf(v1[2*e]*rs*w1[2*e]) | ((u32)f2bf(v1[2*e+1]*rs*w1[2*e+1]) << 16);
  }
  *(u32x4*)(out + (size_t)row*2048 + tid*8) = pk;
}

// ---------------------------------------------------------------------------
// Weight transpose+convert: W[model][K][N] fp32 -> Wt[model][N][K] bf16
// ---------------------------------------------------------------------------
__global__ __launch_bounds__(256) void transpose_w(const float* __restrict__ W,
    u16* __restrict__ Wt, int K, int N)
{
  __shared__ float t[32][33];
  const int n0 = blockIdx.x * 32, k0 = blockIdx.y * 32;
  const float* Wm = W + (size_t)blockIdx.z * K * N;
  u16* Wtm = Wt + (size_t)blockIdx.z * K * N;
  const int tx = threadIdx.x & 31, ty = threadIdx.x >> 5;
  #pragma unroll
  for (int p=0;p<4;++p){
    int k = ty + p*8;
    t[k][tx] = Wm[(size_t)(k0 + k) * N + n0 + tx];
  }
  __syncthreads();
  #pragma unroll
  for (int p=0;p<4;++p){
    int n = ty + p*8;
    Wtm[(size_t)(n0 + n) * K + k0 + tx] = f2bf(t[tx][n]);
  }
}

// ---------------------------------------------------------------------------
// Routed GEMM: C[M,N] = A[M,K](bf16) @ Wt[model][N][K](bf16, pre-transposed)
// 128x128 tile, BK=32, 4 waves (2x2 of 64x64), mfma 16x16x32 bf16.
// Both operands staged via global_load_lds width=16 with pre-swizzled source.
// Grid: x = M-tile fastest (W panel reuse in L2/L3).
// MODE 0: out bf16. MODE 1: out fp32 += residual. MODE 2 (QKV): cols<4096 ->
// bf16 row-major; V cols (>=4096) -> VtOut[seg][h][d][kv] transposed (8B stores).
// ---------------------------------------------------------------------------
template<int MODE>
__global__ __launch_bounds__(256) void gemm_routed(
    const u16* __restrict__ A, int lda, const u16* __restrict__ Wt,
    int N, int K, const int* __restrict__ splitp,
    u16* __restrict__ outB, float* __restrict__ outF, const float* __restrict__ res,
    u16* __restrict__ VtOut)
{
  __shared__ char Asm[8192];   // [128 m][32 k] bf16, 4-slot XOR swizzle
  __shared__ char Bsm[8192];   // [128 n][32 k] bf16, same swizzle
  const int tid = threadIdx.x;
  const int w = tid >> 6, l = tid & 63;
  const int ln = l & 15, g = l >> 4;
  const int wm = w >> 1, wn = w & 1;
  const int row0 = blockIdx.x * 128;   // M-tile fastest
  const int n0 = blockIdx.y * 128;
  const int model = (row0 >= splitp[0]) ? 1 : 0;
  const u16* B = Wt + (size_t)model * N * K;

  f32x4 acc[4][4];
  #pragma unroll
  for (int i=0;i<4;++i)
    #pragma unroll
    for (int j=0;j<4;++j) acc[i][j] = f32x4{0.f,0.f,0.f,0.f};

  // per-lane gll source decode (issue i): linear dest = (w*2+i)*1024 + l*16
  int arow[2], aj[2];
  #pragma unroll
  for (int i=0;i<2;++i){
    int lin = (w*2+i)*1024 + l*16;
    int r_ = lin >> 6;             // 64 B per row
    int s_ = (lin >> 4) & 3;       // 4 slots of 16B
    arow[i] = r_;
    aj[i] = s_ ^ (r_ & 3);         // pre-swizzled k-slot
  }

  const int nt = K / 32;
  for (int kt = 0; kt < nt; ++kt){
    __syncthreads();               // previous tile's reads complete
    #pragma unroll
    for (int i=0;i<2;++i){
      const u16* srcA = A + (size_t)(row0 + arow[i]) * lda + kt*32 + aj[i]*8;
      gload_lds16(srcA, Asm + (w*2+i)*1024);
      const u16* srcB = B + (size_t)(n0 + arow[i]) * K + kt*32 + aj[i]*8;
      gload_lds16(srcB, Bsm + (w*2+i)*1024);
    }
    __syncthreads();               // staging visible (drains vmcnt+lgkm)

    bf16x8 a[4], b[4];
    #pragma unroll
    for (int mf=0;mf<4;++mf){
      int r_ = wm*64 + mf*16 + ln;
      a[mf] = *(const bf16x8*)(Asm + r_*64 + (((g ^ (r_&3)) & 3) << 4));
    }
    #pragma unroll
    for (int nf=0;nf<4;++nf){
      int r_ = wn*64 + nf*16 + ln;
      b[nf] = *(const bf16x8*)(Bsm + r_*64 + (((g ^ (r_&3)) & 3) << 4));
    }
    __builtin_amdgcn_s_setprio(1);
    #pragma unroll
    for (int mf=0;mf<4;++mf)
      #pragma unroll
      for (int nf=0;nf<4;++nf)
        acc[mf][nf] = MFMA16(a[mf], b[nf], acc[mf][nf]);
    __builtin_amdgcn_s_setprio(0);
  }

  if (MODE == 2 && n0 >= 4096) {
    // V columns: store transposed Vt[seg][h][d][kv], r=0..3 are kv-consecutive
    const int seg = (row0 >= 2048) ? 1 : 0;
    const int hh = (n0 - 4096) >> 7;
    u16* vt = VtOut + (size_t)(seg*16 + hh) * 128 * 2048;
    const int kvb = row0 - seg*2048 + wm*64;
    #pragma unroll
    for (int mf=0;mf<4;++mf){
      #pragma unroll
      for (int nf=0;nf<4;++nf){
        int d  = wn*64 + nf*16 + ln;
        int kv = kvb + mf*16 + g*4;
        u16x4 pk = { f2bf(acc[mf][nf][0]), f2bf(acc[mf][nf][1]),
                     f2bf(acc[mf][nf][2]), f2bf(acc[mf][nf][3]) };
        *(u16x4*)(vt + (size_t)d*2048 + kv) = pk;
      }
    }
    return;
  }

  // epilogue: C row = (lane>>4)*4+r, col = lane&15 within each 16x16 frag
  #pragma unroll
  for (int mf=0;mf<4;++mf){
    #pragma unroll
    for (int nf=0;nf<4;++nf){
      #pragma unroll
      for (int r=0;r<4;++r){
        int row = row0 + wm*64 + mf*16 + g*4 + r;
        int col = n0 + wn*64 + nf*16 + ln;
        size_t off = (size_t)row * N + col;
        float v = acc[mf][nf][r];
        if (MODE == 1) outF[off] = v + res[off];
        else           outB[off] = f2bf(v);
      }
    }
  }
}

// ---------------------------------------------------------------------------
// Flash attention per (seg, head, 64-row Q tile). qkv bf16 [4096][6144]:
// q cols [0,2048) k [2048,4096). V comes pre-transposed: Vt[seg][h][128 d][2048 kv].
// Each wave owns 16 q rows. KV tiles of 32, double-buffered, both staged via
// global_load_lds. PV computed as O^T = V^T * P^T.
// ---------------------------------------------------------------------------
__global__ __launch_bounds__(256) void attn_kernel(const u16* __restrict__ qkv,
                                                   const u16* __restrict__ Vt,
                                                   u16* __restrict__ out)
{
  __shared__ char Ksm[2][8192];   // [32 kv][128 d] bf16, 16-slot swizzle
  __shared__ char Vsm[2][8192];   // [128 d][32 kv] bf16, 4-slot swizzle (row>>1)
  __shared__ char Psm[4][1024];   // per wave [16 q][32 kv] bf16, 4-slot swizzle (row>>1)
  const int tid = threadIdx.x;
  const int w = tid >> 6, l = tid & 63;
  const int ln = l & 15, g = l >> 4;
  const int qt = blockIdx.x, h = blockIdx.y, seg = blockIdx.z;
  const int srow = seg * 2048;
  const float scale = 0.08838834764831845f;   // 1/sqrt(128)

  const int qrow = srow + qt*64 + w*16 + ln;
  bf16x8 qf[4];
  #pragma unroll
  for (int c=0;c<4;++c)
    qf[c] = *(const bf16x8*)(qkv + (size_t)qrow*6144 + h*128 + c*32 + g*8);

  f32x4 oacc[8];
  #pragma unroll
  for (int i=0;i<8;++i) oacc[i] = f32x4{0.f,0.f,0.f,0.f};
  float m[4]    = {-1e30f,-1e30f,-1e30f,-1e30f};
  float lsum[4] = {0.f,0.f,0.f,0.f};

  // K staging decode: [32 kv][256B], 16 slots of 16B, slot ^= (kv&15)
  int kkv[2], ks[2];
  #pragma unroll
  for (int i=0;i<2;++i){
    int lin = (w*2+i)*1024 + l*16;
    int kv = lin >> 8;
    int sp = (lin >> 4) & 15;
    kkv[i] = kv;
    ks[i] = sp ^ (kv & 15);
  }
  // V staging decode: [128 d][64B], 4 slots of 16B, slot ^= ((d>>1)&3)
  int vd[2], vs[2];
  #pragma unroll
  for (int i=0;i<2;++i){
    int lin = tid*16 + i*4096;
    int d_ = lin >> 6;
    int sp = (lin >> 4) & 3;
    vd[i] = d_;
    vs[i] = sp ^ ((d_ >> 1) & 3);
  }
  const u16* Vh = Vt + (size_t)(seg*16 + h) * 128 * 2048;

  auto stage = [&](int kv0, int buf){
    #pragma unroll
    for (int i=0;i<2;++i){
      const u16* srcK = qkv + (size_t)(srow + kv0 + kkv[i]) * 6144 + 2048 + h*128 + ks[i]*8;
      gload_lds16(srcK, Ksm[buf] + (w*2+i)*1024);
      const u16* srcV = Vh + (size_t)vd[i] * 2048 + kv0 + vs[i]*8;
      gload_lds16(srcV, Vsm[buf] + w*1024 + i*4096);
    }
  };

  stage(0, 0);
  __syncthreads();

  for (int t=0; t<64; ++t){
    int cur = t & 1, nxt = cur ^ 1;
    if (t+1 < 64) stage((t+1)*32, nxt);   // prefetch next KV

    // S = Q K^T over d=128 (two 16-col halves)
    f32x4 s0 = f32x4{0.f,0.f,0.f,0.f}, s1 = f32x4{0.f,0.f,0.f,0.f};
    __builtin_amdgcn_s_setprio(1);
    #pragma unroll
    for (int c=0;c<4;++c){
      int sl = c*4 + g;
      int c0 = ln;
      bf16x8 k0 = *(const bf16x8*)(Ksm[cur] + c0*256 + (((sl ^ (c0&15)) & 15) << 4));
      s0 = MFMA16(qf[c], k0, s0);
      int c1 = 16 + ln;
      bf16x8 k1 = *(const bf16x8*)(Ksm[cur] + c1*256 + (((sl ^ (c1&15)) & 15) << 4));
      s1 = MFMA16(qf[c], k1, s1);
    }
    __builtin_amdgcn_s_setprio(0);
    float mx[4], f_[4];
    #pragma unroll
    for (int r=0;r<4;++r){
      s0[r] *= scale; s1[r] *= scale;
      mx[r] = fmaxf(s0[r], s1[r]);
    }
    #pragma unroll
    for (int off=1; off<16; off<<=1){
      #pragma unroll
      for (int r=0;r<4;++r) mx[r] = fmaxf(mx[r], __shfl_xor(mx[r], off, 64));
    }
    #pragma unroll
    for (int r=0;r<4;++r){
      float mn = fmaxf(m[r], mx[r]);
      f_[r] = __expf(m[r] - mn);
      m[r] = mn;
      lsum[r] *= f_[r];
    }
    // P = exp(S - m) -> per-wave LDS rows qq=g*4+r, cols ln / 16+ln
    #pragma unroll
    for (int r=0;r<4;++r){
      float p0 = __expf(s0[r] - m[r]);
      float p1 = __expf(s1[r] - m[r]);
      lsum[r] += p0 + p1;
      int qq = g*4 + r;
      int sw = (qq >> 1) & 3;
      int c0 = ln, c1 = 16 + ln;
      *(u16*)(Psm[w] + qq*64 + ((((c0>>3) ^ sw) & 3) << 4) + ((c0&7)<<1)) = f2bf(p0);
      *(u16*)(Psm[w] + qq*64 + ((((c1>>3) ^ sw) & 3) << 4) + ((c1&7)<<1)) = f2bf(p1);
    }
    // redistribute rescale factor to O^T column layout (col q = ln)
    {
      int srcl = (ln >> 2) << 4;
      float F0 = __shfl(f_[0], srcl, 64);
      float F1 = __shfl(f_[1], srcl, 64);
      float F2 = __shfl(f_[2], srcl, 64);
      float F3 = __shfl(f_[3], srcl, 64);
      int rr = ln & 3;
      float fc = (rr==0) ? F0 : (rr==1) ? F1 : (rr==2) ? F2 : F3;
      #pragma unroll
      for (int mc=0;mc<8;++mc){
        #pragma unroll
        for (int r=0;r<4;++r) oacc[mc][r] *= fc;
      }
    }
    // O^T += V^T * P^T
    bf16x8 pf = *(const bf16x8*)(Psm[w] + ln*64 + (((g ^ ((ln>>1)&3)) & 3) << 4));
    __builtin_amdgcn_s_setprio(1);
    #pragma unroll
    for (int mc=0;mc<8;++mc){
      int d = mc*16 + ln;
      bf16x8 vf = *(const bf16x8*)(Vsm[cur] + d*64 + (((g ^ ((d>>1)&3)) & 3) << 4));
      oacc[mc] = MFMA16(vf, pf, oacc[mc]);
    }
    __builtin_amdgcn_s_setprio(0);
    __syncthreads();
  }

  // final: full row sums, redistribute to column layout, normalize, store
  #pragma unroll
  for (int off=1; off<16; off<<=1){
    #pragma unroll
    for (int r=0;r<4;++r) lsum[r] += __shfl_xor(lsum[r], off, 64);
  }
  int srcl = (ln >> 2) << 4;
  float L0 = __shfl(lsum[0], srcl, 64);
  float L1 = __shfl(lsum[1], srcl, 64);
  float L2 = __shfl(lsum[2], srcl, 64);
  float L3 = __shfl(lsum[3], srcl, 64);
  int rr = ln & 3;
  float Lc = (rr==0) ? L0 : (rr==1) ? L1 : (rr==2) ? L2 : L3;
  float linv = 1.0f / Lc;
  const int orow = srow + qt*64 + w*16 + ln;
  #pragma unroll
  for (int mc=0;mc<8;++mc){
    u16x4 pk = { f2bf(oacc[mc][0] * linv), f2bf(oacc[mc][1] * linv),
                 f2bf(oacc[mc][2] * linv), f2bf(oacc[mc][3] * linv) };
    *(u16x4*)(out + (size_t)orow*2048 + h*128 + mc*16 + g*4) = pk;
  }
}

// ---------------------------------------------------------------------------
// SwiGLU: hm[i,j] = silu(gu[i,j]) * gu[i,FF+j], FF=5504, all bf16
// ---------------------------------------------------------------------------
__global__ __launch_bounds__(256) void silu_kernel(const u16* __restrict__ gu,
                                                   u16* __restrict__ hm)
{
  int u = blockIdx.x*256 + threadIdx.x;
  if (u >= 4096*688) return;
  int row = u / 688;
  int j = (u - row*688) * 8;
  const u16* gp = gu + (size_t)row*11008 + j;
  u16x8 gv = *(const u16x8*)gp;
  u16x8 uv = *(const u16x8*)(gp + 5504);
  u32x4 pk;
  #pragma unroll
  for (int e=0;e<4;++e){
    float g0 = bf2f(gv[2*e]),   g1 = bf2f(gv[2*e+1]);
    float u0 = bf2f(uv[2*e]),   u1 = bf2f(uv[2*e+1]);
    float r0 = g0 / (1.f + __expf(-g0)) * u0;
    float r1 = g1 / (1.f + __expf(-g1)) * u1;
    pk[e] = (u32)f2bf(r0) | ((u32)f2bf(r1) << 16);
  }
  *(u32x4*)(hm + (size_t)row*5504 + j) = pk;
}

// ---------------------------------------------------------------------------
extern "C" void kernel_launch(void* const* d_in, const int* in_sizes, int n_in,
                              void* d_out, int out_size, void* d_ws, size_t ws_size,
                              hipStream_t stream) {
  const float* x    = (const float*)d_in[0];
  const float* Wqkv = (const float*)d_in[1];
  const float* Wo   = (const float*)d_in[2];
  const float* Wgu  = (const float*)d_in[3];
  const float* Wd   = (const float*)d_in[4];
  const float* ln1  = (const float*)d_in[5];
  const float* ln2  = (const float*)d_in[6];
  const int*   split= (const int*)d_in[7];
  float* out = (float*)d_out;

  // workspace layout (bytes); total 268,435,456 (256 MiB)
  char* ws = (char*)d_ws;
  u16* Wt   = (u16*)(ws);                  // transposed-weight scratch, <= 90.18 MB
  u16* h    = (u16*)(ws + 94371840);       // [4096][2048] 16.78 MB (also h2)
  u16* qkv  = (u16*)(ws + 111149056);      // [4096][6144] 50.33 MB (also hm)
  u16* attn = (u16*)(ws + 161480704);      // [4096][2048] 16.78 MB
  u16* gu   = (u16*)(ws + 178257920);      // [4096][11008] 90.18 MB
  u16* h2   = h;
  u16* hm   = qkv;
  u16* Vt   = gu;                          // Vt[2][16][128][2048] 16.78 MB, dead before gu written

  // 1. h = rmsnorm(x, ln1)
  rmsnorm_kernel<<<4096, 256, 0, stream>>>(x, ln1, split, h);
  // 2. qkv = h @ W_qkv[model]; V third stored transposed into Vt
  transpose_w<<<dim3(192, 64, 2), 256, 0, stream>>>(Wqkv, Wt, 2048, 6144);
  gemm_routed<2><<<dim3(32, 48), 256, 0, stream>>>(h, 2048, Wt, 6144, 2048, split,
                                                   qkv, nullptr, nullptr, Vt);
  // 3. attention per segment/head
  attn_kernel<<<dim3(32, 16, 2), 256, 0, stream>>>(qkv, Vt, attn);
  // 4. x1 = x + attn @ W_o[model]   (x1 lives in d_out)
  transpose_w<<<dim3(64, 64, 2), 256, 0, stream>>>(Wo, Wt, 2048, 2048);
  gemm_routed<1><<<dim3(32, 16), 256, 0, stream>>>(attn, 2048, Wt, 2048, 2048, split,
                                                   nullptr, out, x, nullptr);
  // 5. h2 = rmsnorm(x1, ln2)
  rmsnorm_kernel<<<4096, 256, 0, stream>>>(out, ln2, split, h2);
  // 6. gu = h2 @ W_gu[model]
  transpose_w<<<dim3(344, 64, 2), 256, 0, stream>>>(Wgu, Wt, 2048, 11008);
  gemm_routed<0><<<dim3(32, 86), 256, 0, stream>>>(h2, 2048, Wt, 11008, 2048, split,
                                                   gu, nullptr, nullptr, nullptr);
  // 7. hm = silu(gate) * up
  silu_kernel<<<11008, 256, 0, stream>>>(gu, hm);
  // 8. out = x1 + hm @ W_d[model]
  transpose_w<<<dim3(64, 172, 2), 256, 0, stream>>>(Wd, Wt, 5504, 2048);
  gemm_routed<1><<<dim3(32, 16), 256, 0, stream>>>(hm, 5504, Wt, 2048, 5504, split,
                                                   nullptr, out, out, nullptr);
}